// Round 8
// baseline (323.851 us; speedup 1.0000x reference)
//
#include <hip/hip_runtime.h>
#include <stdint.h>

#define D_MODEL 1024
#define NHEAD 16
#define HEAD_DIM 64
#define BATCH 4
#define SEQ 2048
#define ROWS (BATCH*SEQ)   // 8192

typedef __attribute__((ext_vector_type(8))) short short8;
typedef __attribute__((ext_vector_type(4))) float f32x4;
typedef __attribute__((ext_vector_type(2))) unsigned int u32x2;
typedef unsigned short u16;
typedef unsigned int u32;

// log2(e)/8 folded into Q at projection time
#define QSCALE 0.18033688011112042f

// fp32 -> bf16 round-to-nearest-even
__device__ __forceinline__ u16 f2b(float f) {
  union { float f; uint32_t u; } in; in.f = f;
  uint32_t u = in.u;
  return (u16)((u + 0x7FFFu + ((u >> 16) & 1u)) >> 16);
}

// async global->LDS, 16B/lane; HW dest = wave-uniform base + lane*16
__device__ __forceinline__ void async_lds16(const void* g, void* l) {
  __builtin_amdgcn_global_load_lds(
      (const __attribute__((address_space(1))) uint32_t*)g,
      (__attribute__((address_space(3))) uint32_t*)l,
      16, 0, 0);
}

// pack two f32 into bf16x2 (round-half-up)
__device__ __forceinline__ u32 pack_bf16(float lo, float hi) {
  union { float f; uint32_t u; } a, b; a.f = lo; b.f = hi;
  return __builtin_amdgcn_perm(b.u + 0x8000u, a.u + 0x8000u, 0x07060302u);
}

// ---------------- fp32 -> bf16 bulk convert (x and y fused) ----------------
__global__ void __launch_bounds__(256) cvt_kernel(const float* __restrict__ x,
                                                  const float* __restrict__ y,
                                                  u16* __restrict__ xb,
                                                  u16* __restrict__ yb) {
  const float* in = blockIdx.y ? y : x;
  u16* out = blockIdx.y ? yb : xb;
  int i = blockIdx.x * 256 + threadIdx.x;
  float4 v = ((const float4*)in)[i];
  ushort4 o;
  o.x = f2b(v.x); o.y = f2b(v.y); o.z = f2b(v.z); o.w = f2b(v.w);
  ((ushort4*)out)[i] = o;
}

// ---------------- weight transpose + convert (4 weights fused via z) ----------------
__global__ void __launch_bounds__(256) wtrans_kernel(const float* __restrict__ wq,
                                                     const float* __restrict__ wk,
                                                     const float* __restrict__ wv,
                                                     const float* __restrict__ wo,
                                                     u16* __restrict__ wtbase) {
  __shared__ u16 tile[64 * 65];
  int z = blockIdx.z;
  const float* w = (z == 0) ? wq : (z == 1 ? wk : (z == 2 ? wv : wo));
  u16* wt = wtbase + (size_t)z * D_MODEL * D_MODEL;
  int t = threadIdx.x;
  int c = t & 63, rb = t >> 6;
  int k0 = blockIdx.x * 64, n0 = blockIdx.y * 64;
#pragma unroll
  for (int i = 0; i < 16; ++i) {
    int r = rb + i * 4;
    tile[c * 65 + r] = f2b(w[(size_t)(k0 + r) * D_MODEL + n0 + c]);
  }
  __syncthreads();
#pragma unroll
  for (int i = 0; i < 16; ++i) {
    int r = rb + i * 4;
    wt[(size_t)(n0 + r) * D_MODEL + k0 + c] = tile[r * 65 + c];
  }
}

// ---------------- GEMM core: C[M][N] = A[M][K] * Bt[N][K]^T + bias ----------------
// Serial BK=64 loop (m97 structure, round-5 verified best) + caller-hoisted
// 32 KB LDS (round 4: per-instantiation __shared__ dup'd to 64 KB -> 2 blk/CU).
// 128x128 tile, 4 waves (2x2), 4x4 accs.
// MODE 0 (bf16 out) / MODE 1 (f32 out): OPERAND-SWAPPED (weights in MFMA-A slot)
//   so D's reg-dim = output columns -> vectorized 8B/16B stores.
// MODE 2: V^T sigma-layout out, natural orientation, packed across ni.
template <int MODE>
__device__ __forceinline__ void gemm_bt_core(const u16* __restrict__ A,
                                             const u16* __restrict__ Bt,
                                             const float* __restrict__ bias,
                                             void* __restrict__ Cout, float scale,
                                             int m0, int n0,
                                             u16 (* __restrict__ As)[128 * 32],
                                             u16 (* __restrict__ Bs)[128 * 32]) {
  constexpr int K = 1024, N = 1024;
  constexpr bool SWAP = (MODE != 2);
  int tid = threadIdx.x;
  int wave = tid >> 6, lane = tid & 63;
  int quad = lane >> 4, l16 = lane & 15;
  int wm = wave & 1, wn = wave >> 1;

  f32x4 acc[4][4];
#pragma unroll
  for (int p = 0; p < 4; ++p)
#pragma unroll
    for (int q = 0; q < 4; ++q) acc[p][q] = f32x4{0.f, 0.f, 0.f, 0.f};

  int srow = lane >> 2;
  int scol = (lane & 3) * 16;  // bytes

  for (int k0 = 0; k0 < K; k0 += 64) {
#pragma unroll
    for (int kh = 0; kh < 2; ++kh) {
#pragma unroll
      for (int i = 0; i < 2; ++i) {
        int c = wave * 2 + i;
        const char* ga = (const char*)(A + (size_t)(m0 + c * 16 + srow) * K + k0 + kh * 32) + scol;
        async_lds16(ga, (char*)As[kh] + c * 1024);
        const char* gb = (const char*)(Bt + (size_t)(n0 + c * 16 + srow) * K + k0 + kh * 32) + scol;
        async_lds16(gb, (char*)Bs[kh] + c * 1024);
      }
    }
    __syncthreads();  // drains staging

#pragma unroll
    for (int kh = 0; kh < 2; ++kh) {
      short8 fa[4], fb[4];
#pragma unroll
      for (int p = 0; p < 4; ++p)
        fa[p] = SWAP
          ? *(const short8*)(Bs[kh] + (wn * 64 + p * 16 + l16) * 32 + quad * 8)
          : *(const short8*)(As[kh] + (wm * 64 + p * 16 + l16) * 32 + quad * 8);
#pragma unroll
      for (int q = 0; q < 4; ++q)
        fb[q] = SWAP
          ? *(const short8*)(As[kh] + (wm * 64 + q * 16 + l16) * 32 + quad * 8)
          : *(const short8*)(Bs[kh] + (wn * 64 + q * 16 + l16) * 32 + quad * 8);
#pragma unroll
      for (int p = 0; p < 4; ++p)
#pragma unroll
        for (int q = 0; q < 4; ++q)
          acc[p][q] = __builtin_amdgcn_mfma_f32_16x16x32_bf16(fa[p], fb[q], acc[p][q], 0, 0, 0);
    }
    __syncthreads();
  }

  if (MODE == 2) {
    // acc[p][q]: D-row (quad*4+r) = d-dim (wvT row), D-col (l16) = s within q*16 block.
    int sblk = n0 + wn * 64;               // 64-aligned s block; all s in same batch b
    int bb = sblk >> 11;
    int ssb = sblk & 2047;
#pragma unroll
    for (int p = 0; p < 4; ++p) {
      int dbase = m0 + wm * 64 + p * 16 + quad * 4;
      float4 b4 = *(const float4*)(bias + dbase);
#pragma unroll
      for (int r = 0; r < 4; ++r) {
        int d = dbase + r;
        float bv = ((const float*)&b4)[r];
        u32 lo = pack_bf16(acc[p][0][r] + bv, acc[p][1][r] + bv);
        u32 hi = pack_bf16(acc[p][2][r] + bv, acc[p][3][r] + bv);
        size_t vtrow = ((size_t)bb * 16 + (d >> 6)) * 64 + (d & 63);
        *(u32x2*)((u16*)Cout + vtrow * 2048 + ssb + 4 * l16) = u32x2{lo, hi};
      }
    }
  } else {
    // SWAPPED: acc[p][q]: D-row (quad*4+r) = out-col n, D-col (l16) = out-row m.
#pragma unroll
    for (int p = 0; p < 4; ++p) {
      int nbase = n0 + wn * 64 + p * 16 + quad * 4;
      float4 b4 = *(const float4*)(bias + nbase);
#pragma unroll
      for (int q = 0; q < 4; ++q) {
        size_t mrow = (size_t)(m0 + wm * 64 + q * 16 + l16);
        float v0 = (acc[p][q][0] + b4.x) * scale;
        float v1 = (acc[p][q][1] + b4.y) * scale;
        float v2 = (acc[p][q][2] + b4.z) * scale;
        float v3 = (acc[p][q][3] + b4.w) * scale;
        if (MODE == 1) {
          *(f32x4*)((float*)Cout + mrow * N + nbase) = f32x4{v0, v1, v2, v3};
        } else {
          *(u32x2*)((u16*)Cout + mrow * N + nbase) = u32x2{pack_bf16(v0, v1), pack_bf16(v2, v3)};
        }
      }
    }
  }
}

// QKV fused: grid (512, 3). z=0: Q=x*wq (scaled); z=1: K=y*wk; z=2: V^T sigma
// T1 XCD swizzle (round 6, WIN): linear id = bx + z*512 -> XCD = bx & 7.
// Each XCD owns a contiguous 8-m-block stripe (2 MB of the 16 MB activation) x
// all 8 weight n-blocks -> per-XCD working set ~4 MB = one L2. z=2 swaps roles.
__global__ void __launch_bounds__(256, 4) gemm_qkv_kernel(
    const u16* __restrict__ xb, const u16* __restrict__ yb,
    const u16* __restrict__ wqT, const u16* __restrict__ wkT, const u16* __restrict__ wvT,
    const float* __restrict__ bq, const float* __restrict__ bk, const float* __restrict__ bv,
    u16* __restrict__ q, u16* __restrict__ k, u16* __restrict__ vt) {
  // single 32 KB allocation shared by all gemm_bt_core instantiations
  __shared__ u16 As[2][128 * 32];
  __shared__ u16 Bs[2][128 * 32];
  int bx = blockIdx.x, z = blockIdx.y;
  int xcd = bx & 7, i = bx >> 3;
  int stripe = (xcd * 8 + (i >> 3)) * 128;  // 64 blocks of the 16MB-array dim
  int other  = (i & 7) * 128;               // 8 blocks of the 1K weight dim
  if (z == 0) {
    gemm_bt_core<0>(xb, wqT, bq, q, QSCALE, stripe, other, As, Bs);
  } else if (z == 1) {
    gemm_bt_core<0>(yb, wkT, bk, k, 1.0f, stripe, other, As, Bs);
  } else {
    gemm_bt_core<2>(wvT, yb, bv, vt, 1.0f, other, stripe, As, Bs);
  }
}

// grid (8, 64): XCD bx owns m-stripe bx*8+(by>>3), n = by&7 (bijective).
__global__ void __launch_bounds__(256, 4) gemm_o_kernel(const u16* __restrict__ ao,
                                                        const u16* __restrict__ woT,
                                                        const float* __restrict__ bo,
                                                        float* __restrict__ out) {
  __shared__ u16 As[2][128 * 32];
  __shared__ u16 Bs[2][128 * 32];
  int bx = blockIdx.x, by = blockIdx.y;
  int m0 = (bx * 8 + (by >> 3)) * 128;
  int n0 = (by & 7) * 128;
  gemm_bt_core<1>(ao, woT, bo, out, 1.0f, m0, n0, As, Bs);
}

// ---------------- flash attention: no-max softmax, dbuf K/V, single barrier ------
// grid (B*H, SEQ/128): bh-major -> all q-blocks of one bh share an XCD's L2 KV.
// Block 256 = 4 waves; wave owns 32 q-rows (2 rowsets of 16); kv-tile 64 keys.
// V MUST stay LDS-staged (round-1: direct V reads -> FETCH 32->812MB, 4x dur).
// Round 7: l = P x ones on the MFMA pipe (WIN, 99->91us, MfmaUtil 30->36).
// ROUND 8: tile loop unrolled x2 so the dbuf index CUR is COMPILE-TIME, plus all
// swizzled LDS offsets precomputed (kfo/vo/pwo/pao, const-indexed per rule #20)
// and global prefetch pointers advanced incrementally. Rationale: VGPR=64 shows
// the compiler re-derived every LDS address per tile (buffer index was runtime);
// with CUR constant it can hold lane offsets in VGPRs (budget 128) and fold
// buffer selection into ds offset immediates -> in-loop VALU addressing ~0.
// LDS total = 16 (Ks dbuf) + 16 (Vts dbuf) + 8 (Ps) = 40 KB -> 4 blocks/CU.
__global__ void __launch_bounds__(256, 4) attn_kernel(const u16* __restrict__ Q,
                                                      const u16* __restrict__ Kp,
                                                      const u16* __restrict__ Vt,
                                                      u16* __restrict__ Outp) {
  __shared__ u16 Ks[2][64 * 64];     // [key][d-chunk^key&7]
  __shared__ u16 Vts[2][64 * 64];    // [d][sigma-chunk^d&7]
  __shared__ u16 Ps[4][16 * 64];     // per-wave P [row][sigma-chunk^row&7]

  int tid = threadIdx.x, wave = tid >> 6, lane = tid & 63;
  int quad = lane >> 4, l16 = lane & 15;
  int bh = blockIdx.x;
  int b = bh >> 4, h = bh & 15;
  int q0 = blockIdx.y * 128 + wave * 32;
  size_t gbase = (size_t)b * SEQ * D_MODEL;
  const u16* kbase = Kp + gbase + (size_t)h * HEAD_DIM;
  const u16* vbase = Vt + (size_t)bh * HEAD_DIM * SEQ;
  const u16* qrow = Q + gbase + (size_t)q0 * D_MODEL + (size_t)h * HEAD_DIM;

  // Q A-frags (scale pre-folded): aq[rowset][k-half]
  short8 aq[2][2];
#pragma unroll
  for (int rs = 0; rs < 2; ++rs)
#pragma unroll
    for (int dc = 0; dc < 2; ++dc)
      aq[rs][dc] = *(const short8*)(qrow + (size_t)(rs * 16 + l16) * D_MODEL + dc * 32 + quad * 8);

  // constant all-ones bf16 B-fragment (1.0 = 0x3F80) for the l = P*ones MFMA
  const short8 onesb = short8{0x3F80, 0x3F80, 0x3F80, 0x3F80,
                              0x3F80, 0x3F80, 0x3F80, 0x3F80};

  f32x4 Oacc[2][4];
  f32x4 Lacc[2];
#pragma unroll
  for (int rs = 0; rs < 2; ++rs) {
#pragma unroll
    for (int ni = 0; ni < 4; ++ni) Oacc[rs][ni] = f32x4{0.f, 0.f, 0.f, 0.f};
    Lacc[rs] = f32x4{0.f, 0.f, 0.f, 0.f};
  }

  // staging offsets (u16 units), chunk c = i*256 + tid
  size_t koff[2], voff[2];
  int dstoff[2];
#pragma unroll
  for (int i = 0; i < 2; ++i) {
    int c = i * 256 + tid;
    int krow = c >> 3, kgp = c & 7;
    koff[i] = (size_t)krow * D_MODEL + (size_t)((kgp ^ (krow & 7)) * 8);
    voff[i] = (size_t)krow * SEQ + (size_t)((kgp ^ (krow & 7)) * 8);
    dstoff[i] = i * 4096 + wave * 1024;  // bytes within one buffer
  }

  // ---- loop-invariant swizzled LDS offsets (u16 units; const-indexed only) ----
  int x = l16 & 7;
  int kfo[4][2], pao[2], vo[2][4], pwo[4];
#pragma unroll
  for (int sub = 0; sub < 4; ++sub) {
    kfo[sub][0] = (sub * 16 + l16) * 64 + ((quad ^ x) << 3);
    kfo[sub][1] = (sub * 16 + l16) * 64 + (((4 + quad) ^ x) << 3);
  }
#pragma unroll
  for (int kc = 0; kc < 2; ++kc) {
    pao[kc] = l16 * 64 + ((((kc << 2) + quad) ^ x) << 3);
#pragma unroll
    for (int ni = 0; ni < 4; ++ni)
      vo[kc][ni] = (ni * 16 + l16) * 64 + ((((kc << 2) + quad) ^ x) << 3);
  }
#pragma unroll
  for (int r = 0; r < 4; ++r) {
    int row = quad * 4 + r;
    pwo[r] = row * 64 + (((l16 >> 1) ^ (row & 7)) << 3) + ((l16 & 1) << 2);
  }
  u16* Pw = Ps[wave];

  // prologue: stage tile 0 into buffer 0; prefetch pointers start at tile 1
#pragma unroll
  for (int i = 0; i < 2; ++i) {
    async_lds16(kbase + koff[i], (char*)Ks[0] + dstoff[i]);
    async_lds16(vbase + voff[i], (char*)Vts[0] + dstoff[i]);
  }
  const u16* kp[2];
  const u16* vp[2];
#pragma unroll
  for (int i = 0; i < 2; ++i) {
    kp[i] = kbase + (size_t)64 * D_MODEL + koff[i];
    vp[i] = vbase + 64 + voff[i];
  }

  constexpr int NT = SEQ / 64;  // 32 tiles
  for (int t = 0; t < NT; t += 2) {
#pragma unroll
    for (int half = 0; half < 2; ++half) {     // CUR compile-time after unroll
      const int CUR = half;
      const int T = t + half;
      __syncthreads();  // drains tile T staging; closes prior reads of buf[CUR^1]
      if (T + 1 < NT) {
#pragma unroll
        for (int i = 0; i < 2; ++i) {
          async_lds16(kp[i], (char*)Ks[CUR ^ 1] + dstoff[i]);
          async_lds16(vp[i], (char*)Vts[CUR ^ 1] + dstoff[i]);
        }
      }
#pragma unroll
      for (int i = 0; i < 2; ++i) {
        kp[i] += (size_t)64 * D_MODEL;
        vp[i] += 64;
      }

      const u16* Kc = Ks[CUR];
      const u16* Vc = Vts[CUR];

      // K B-frags hoisted (shared across both row-sets)
      short8 kf[4][2];
#pragma unroll
      for (int sub = 0; sub < 4; ++sub) {
        kf[sub][0] = *(const short8*)(Kc + kfo[sub][0]);
        kf[sub][1] = *(const short8*)(Kc + kfo[sub][1]);
      }

      short8 pa[2][2];  // [rs][kc]
#pragma unroll
      for (int rs = 0; rs < 2; ++rs) {
        f32x4 S[4];
        __builtin_amdgcn_s_setprio(1);
#pragma unroll
        for (int sub = 0; sub < 4; ++sub) {
          f32x4 s = f32x4{0.f, 0.f, 0.f, 0.f};
          s = __builtin_amdgcn_mfma_f32_16x16x32_bf16(aq[rs][0], kf[sub][0], s, 0, 0, 0);
          s = __builtin_amdgcn_mfma_f32_16x16x32_bf16(aq[rs][1], kf[sub][1], s, 0, 0, 0);
          S[sub] = s;
        }
        __builtin_amdgcn_s_setprio(0);
#pragma unroll
        for (int r = 0; r < 4; ++r) {
          float p0 = __builtin_amdgcn_exp2f(S[0][r]);
          float p1 = __builtin_amdgcn_exp2f(S[1][r]);
          float p2 = __builtin_amdgcn_exp2f(S[2][r]);
          float p3 = __builtin_amdgcn_exp2f(S[3][r]);
          u32 lo = pack_bf16(p0, p1);
          u32 hi = pack_bf16(p2, p3);
          *(u32x2*)(Pw + pwo[r]) = u32x2{lo, hi};
        }
        // read back this rowset's P A-frags before rs1 overwrites the region
#pragma unroll
        for (int kc = 0; kc < 2; ++kc)
          pa[rs][kc] = *(const short8*)(Pw + pao[kc]);
      }

      // PV: O += P * V ; and l += P * ones on the MFMA pipe
      __builtin_amdgcn_s_setprio(1);
#pragma unroll
      for (int kc = 0; kc < 2; ++kc) {
        Lacc[0] = __builtin_amdgcn_mfma_f32_16x16x32_bf16(pa[0][kc], onesb, Lacc[0], 0, 0, 0);
        Lacc[1] = __builtin_amdgcn_mfma_f32_16x16x32_bf16(pa[1][kc], onesb, Lacc[1], 0, 0, 0);
#pragma unroll
        for (int ni = 0; ni < 4; ++ni) {
          short8 bv = *(const short8*)(Vc + vo[kc][ni]);
          Oacc[0][ni] = __builtin_amdgcn_mfma_f32_16x16x32_bf16(pa[0][kc], bv, Oacc[0][ni], 0, 0, 0);
          Oacc[1][ni] = __builtin_amdgcn_mfma_f32_16x16x32_bf16(pa[1][kc], bv, Oacc[1][ni], 0, 0, 0);
        }
      }
      __builtin_amdgcn_s_setprio(0);
    }
  }

  // epilogue: l comes straight from Lacc (all 16 D-cols identical; row=quad*4+r)
#pragma unroll
  for (int rs = 0; rs < 2; ++rs)
#pragma unroll
    for (int r = 0; r < 4; ++r) {
      float inv = 1.0f / Lacc[rs][r];
      size_t orow = gbase + (size_t)(q0 + rs * 16 + quad * 4 + r) * D_MODEL + (size_t)h * HEAD_DIM;
#pragma unroll
      for (int ni = 0; ni < 4; ++ni)
        Outp[orow + ni * 16 + l16] = f2b(Oacc[rs][ni][r] * inv);
    }
}

// ---------------- launch ----------------
extern "C" void kernel_launch(void* const* d_in, const int* in_sizes, int n_in,
                              void* d_out, int out_size, void* d_ws, size_t ws_size,
                              hipStream_t stream) {
  const float* x  = (const float*)d_in[0];
  const float* y  = (const float*)d_in[1];
  const float* wq = (const float*)d_in[2];
  const float* bq = (const float*)d_in[3];
  const float* wk = (const float*)d_in[4];
  const float* bk = (const float*)d_in[5];
  const float* wv = (const float*)d_in[6];
  const float* bv = (const float*)d_in[7];
  const float* wo = (const float*)d_in[8];
  const float* bo = (const float*)d_in[9];
  float* out = (float*)d_out;

  char* ws = (char*)d_ws;
  const size_t SZ_ACT = (size_t)ROWS * D_MODEL * 2;     // 16 MiB
  const size_t SZ_W   = (size_t)D_MODEL * D_MODEL * 2;  // 2 MiB
  u16* xb  = (u16*)(ws);
  u16* yb  = (u16*)(ws + SZ_ACT);
  u16* wT  = (u16*)(ws + 2 * SZ_ACT);
  u16* wqT = wT;
  u16* wkT = (u16*)(ws + 2 * SZ_ACT + SZ_W);
  u16* wvT = (u16*)(ws + 2 * SZ_ACT + 2 * SZ_W);
  u16* woT = (u16*)(ws + 2 * SZ_ACT + 3 * SZ_W);
  u16* qb  = (u16*)(ws + 2 * SZ_ACT + 4 * SZ_W);
  u16* kb  = (u16*)(ws + 3 * SZ_ACT + 4 * SZ_W);
  u16* vt  = (u16*)(ws + 4 * SZ_ACT + 4 * SZ_W);
  u16* ao  = (u16*)(ws + 5 * SZ_ACT + 4 * SZ_W);

  cvt_kernel<<<dim3(8192, 2), 256, 0, stream>>>(x, y, xb, yb);
  wtrans_kernel<<<dim3(16, 16, 4), 256, 0, stream>>>(wq, wk, wv, wo, wT);
  gemm_qkv_kernel<<<dim3(512, 3), 256, 0, stream>>>(xb, yb, wqT, wkT, wvT, bq, bk, bv, qb, kb, vt);
  attn_kernel<<<dim3(64, 16), 256, 0, stream>>>(qb, kb, vt, ao);
  gemm_o_kernel<<<dim3(8, 64), 256, 0, stream>>>(ao, woT, bo, out);
}

// Round 9
// 315.481 us; speedup vs baseline: 1.0265x; 1.0265x over previous
//
#include <hip/hip_runtime.h>
#include <stdint.h>

#define D_MODEL 1024
#define NHEAD 16
#define HEAD_DIM 64
#define BATCH 4
#define SEQ 2048
#define ROWS (BATCH*SEQ)   // 8192

typedef __attribute__((ext_vector_type(8))) short short8;
typedef __attribute__((ext_vector_type(4))) float f32x4;
typedef __attribute__((ext_vector_type(2))) unsigned int u32x2;
typedef unsigned short u16;
typedef unsigned int u32;

// log2(e)/8 folded into Q at projection time
#define QSCALE 0.18033688011112042f

// fp32 -> bf16 round-to-nearest-even
__device__ __forceinline__ u16 f2b(float f) {
  union { float f; uint32_t u; } in; in.f = f;
  uint32_t u = in.u;
  return (u16)((u + 0x7FFFu + ((u >> 16) & 1u)) >> 16);
}

// async global->LDS, 16B/lane; HW dest = wave-uniform base + lane*16
__device__ __forceinline__ void async_lds16(const void* g, void* l) {
  __builtin_amdgcn_global_load_lds(
      (const __attribute__((address_space(1))) uint32_t*)g,
      (__attribute__((address_space(3))) uint32_t*)l,
      16, 0, 0);
}

// pack two f32 into bf16x2 (round-half-up)
__device__ __forceinline__ u32 pack_bf16(float lo, float hi) {
  union { float f; uint32_t u; } a, b; a.f = lo; b.f = hi;
  return __builtin_amdgcn_perm(b.u + 0x8000u, a.u + 0x8000u, 0x07060302u);
}

// ---------------- fp32 -> bf16 bulk convert (x and y fused) ----------------
__global__ void __launch_bounds__(256) cvt_kernel(const float* __restrict__ x,
                                                  const float* __restrict__ y,
                                                  u16* __restrict__ xb,
                                                  u16* __restrict__ yb) {
  const float* in = blockIdx.y ? y : x;
  u16* out = blockIdx.y ? yb : xb;
  int i = blockIdx.x * 256 + threadIdx.x;
  float4 v = ((const float4*)in)[i];
  ushort4 o;
  o.x = f2b(v.x); o.y = f2b(v.y); o.z = f2b(v.z); o.w = f2b(v.w);
  ((ushort4*)out)[i] = o;
}

// ---------------- weight transpose + convert (4 weights fused via z) ----------------
__global__ void __launch_bounds__(256) wtrans_kernel(const float* __restrict__ wq,
                                                     const float* __restrict__ wk,
                                                     const float* __restrict__ wv,
                                                     const float* __restrict__ wo,
                                                     u16* __restrict__ wtbase) {
  __shared__ u16 tile[64 * 65];
  int z = blockIdx.z;
  const float* w = (z == 0) ? wq : (z == 1 ? wk : (z == 2 ? wv : wo));
  u16* wt = wtbase + (size_t)z * D_MODEL * D_MODEL;
  int t = threadIdx.x;
  int c = t & 63, rb = t >> 6;
  int k0 = blockIdx.x * 64, n0 = blockIdx.y * 64;
#pragma unroll
  for (int i = 0; i < 16; ++i) {
    int r = rb + i * 4;
    tile[c * 65 + r] = f2b(w[(size_t)(k0 + r) * D_MODEL + n0 + c]);
  }
  __syncthreads();
#pragma unroll
  for (int i = 0; i < 16; ++i) {
    int r = rb + i * 4;
    wt[(size_t)(n0 + r) * D_MODEL + k0 + c] = tile[r * 65 + c];
  }
}

// ---------------- GEMM core: C[M][N] = A[M][K] * Bt[N][K]^T + bias ----------------
// Serial BK=64 loop (m97 structure, round-5 verified best) + caller-hoisted
// 32 KB LDS (round 4: per-instantiation __shared__ dup'd to 64 KB -> 2 blk/CU).
// 128x128 tile, 4 waves (2x2), 4x4 accs.
// MODE 0 (bf16 out) / MODE 1 (f32 out): OPERAND-SWAPPED (weights in MFMA-A slot)
//   so D's reg-dim = output columns -> vectorized 8B/16B stores.
// MODE 2: V^T sigma-layout out, natural orientation, packed across ni.
template <int MODE>
__device__ __forceinline__ void gemm_bt_core(const u16* __restrict__ A,
                                             const u16* __restrict__ Bt,
                                             const float* __restrict__ bias,
                                             void* __restrict__ Cout, float scale,
                                             int m0, int n0,
                                             u16 (* __restrict__ As)[128 * 32],
                                             u16 (* __restrict__ Bs)[128 * 32]) {
  constexpr int K = 1024, N = 1024;
  constexpr bool SWAP = (MODE != 2);
  int tid = threadIdx.x;
  int wave = tid >> 6, lane = tid & 63;
  int quad = lane >> 4, l16 = lane & 15;
  int wm = wave & 1, wn = wave >> 1;

  f32x4 acc[4][4];
#pragma unroll
  for (int p = 0; p < 4; ++p)
#pragma unroll
    for (int q = 0; q < 4; ++q) acc[p][q] = f32x4{0.f, 0.f, 0.f, 0.f};

  int srow = lane >> 2;
  int scol = (lane & 3) * 16;  // bytes

  for (int k0 = 0; k0 < K; k0 += 64) {
#pragma unroll
    for (int kh = 0; kh < 2; ++kh) {
#pragma unroll
      for (int i = 0; i < 2; ++i) {
        int c = wave * 2 + i;
        const char* ga = (const char*)(A + (size_t)(m0 + c * 16 + srow) * K + k0 + kh * 32) + scol;
        async_lds16(ga, (char*)As[kh] + c * 1024);
        const char* gb = (const char*)(Bt + (size_t)(n0 + c * 16 + srow) * K + k0 + kh * 32) + scol;
        async_lds16(gb, (char*)Bs[kh] + c * 1024);
      }
    }
    __syncthreads();  // drains staging

#pragma unroll
    for (int kh = 0; kh < 2; ++kh) {
      short8 fa[4], fb[4];
#pragma unroll
      for (int p = 0; p < 4; ++p)
        fa[p] = SWAP
          ? *(const short8*)(Bs[kh] + (wn * 64 + p * 16 + l16) * 32 + quad * 8)
          : *(const short8*)(As[kh] + (wm * 64 + p * 16 + l16) * 32 + quad * 8);
#pragma unroll
      for (int q = 0; q < 4; ++q)
        fb[q] = SWAP
          ? *(const short8*)(As[kh] + (wm * 64 + q * 16 + l16) * 32 + quad * 8)
          : *(const short8*)(Bs[kh] + (wn * 64 + q * 16 + l16) * 32 + quad * 8);
#pragma unroll
      for (int p = 0; p < 4; ++p)
#pragma unroll
        for (int q = 0; q < 4; ++q)
          acc[p][q] = __builtin_amdgcn_mfma_f32_16x16x32_bf16(fa[p], fb[q], acc[p][q], 0, 0, 0);
    }
    __syncthreads();
  }

  if (MODE == 2) {
    // acc[p][q]: D-row (quad*4+r) = d-dim (wvT row), D-col (l16) = s within q*16 block.
    int sblk = n0 + wn * 64;               // 64-aligned s block; all s in same batch b
    int bb = sblk >> 11;
    int ssb = sblk & 2047;
#pragma unroll
    for (int p = 0; p < 4; ++p) {
      int dbase = m0 + wm * 64 + p * 16 + quad * 4;
      float4 b4 = *(const float4*)(bias + dbase);
#pragma unroll
      for (int r = 0; r < 4; ++r) {
        int d = dbase + r;
        float bv = ((const float*)&b4)[r];
        u32 lo = pack_bf16(acc[p][0][r] + bv, acc[p][1][r] + bv);
        u32 hi = pack_bf16(acc[p][2][r] + bv, acc[p][3][r] + bv);
        size_t vtrow = ((size_t)bb * 16 + (d >> 6)) * 64 + (d & 63);
        *(u32x2*)((u16*)Cout + vtrow * 2048 + ssb + 4 * l16) = u32x2{lo, hi};
      }
    }
  } else {
    // SWAPPED: acc[p][q]: D-row (quad*4+r) = out-col n, D-col (l16) = out-row m.
#pragma unroll
    for (int p = 0; p < 4; ++p) {
      int nbase = n0 + wn * 64 + p * 16 + quad * 4;
      float4 b4 = *(const float4*)(bias + nbase);
#pragma unroll
      for (int q = 0; q < 4; ++q) {
        size_t mrow = (size_t)(m0 + wm * 64 + q * 16 + l16);
        float v0 = (acc[p][q][0] + b4.x) * scale;
        float v1 = (acc[p][q][1] + b4.y) * scale;
        float v2 = (acc[p][q][2] + b4.z) * scale;
        float v3 = (acc[p][q][3] + b4.w) * scale;
        if (MODE == 1) {
          *(f32x4*)((float*)Cout + mrow * N + nbase) = f32x4{v0, v1, v2, v3};
        } else {
          *(u32x2*)((u16*)Cout + mrow * N + nbase) = u32x2{pack_bf16(v0, v1), pack_bf16(v2, v3)};
        }
      }
    }
  }
}

// QKV fused: grid (512, 3). z=0: Q=x*wq (scaled); z=1: K=y*wk; z=2: V^T sigma
// T1 XCD swizzle (round 6, WIN): linear id = bx + z*512 -> XCD = bx & 7.
// Each XCD owns a contiguous 8-m-block stripe (2 MB of the 16 MB activation) x
// all 8 weight n-blocks -> per-XCD working set ~4 MB = one L2. z=2 swaps roles.
__global__ void __launch_bounds__(256, 4) gemm_qkv_kernel(
    const u16* __restrict__ xb, const u16* __restrict__ yb,
    const u16* __restrict__ wqT, const u16* __restrict__ wkT, const u16* __restrict__ wvT,
    const float* __restrict__ bq, const float* __restrict__ bk, const float* __restrict__ bv,
    u16* __restrict__ q, u16* __restrict__ k, u16* __restrict__ vt) {
  // single 32 KB allocation shared by all gemm_bt_core instantiations
  __shared__ u16 As[2][128 * 32];
  __shared__ u16 Bs[2][128 * 32];
  int bx = blockIdx.x, z = blockIdx.y;
  int xcd = bx & 7, i = bx >> 3;
  int stripe = (xcd * 8 + (i >> 3)) * 128;  // 64 blocks of the 16MB-array dim
  int other  = (i & 7) * 128;               // 8 blocks of the 1K weight dim
  if (z == 0) {
    gemm_bt_core<0>(xb, wqT, bq, q, QSCALE, stripe, other, As, Bs);
  } else if (z == 1) {
    gemm_bt_core<0>(yb, wkT, bk, k, 1.0f, stripe, other, As, Bs);
  } else {
    gemm_bt_core<2>(wvT, yb, bv, vt, 1.0f, other, stripe, As, Bs);
  }
}

// grid (8, 64): XCD bx owns m-stripe bx*8+(by>>3), n = by&7 (bijective).
__global__ void __launch_bounds__(256, 4) gemm_o_kernel(const u16* __restrict__ ao,
                                                        const u16* __restrict__ woT,
                                                        const float* __restrict__ bo,
                                                        float* __restrict__ out) {
  __shared__ u16 As[2][128 * 32];
  __shared__ u16 Bs[2][128 * 32];
  int bx = blockIdx.x, by = blockIdx.y;
  int m0 = (bx * 8 + (by >> 3)) * 128;
  int n0 = (by & 7) * 128;
  gemm_bt_core<1>(ao, woT, bo, out, 1.0f, m0, n0, As, Bs);
}

// ---------------- flash attention: no-max softmax, dbuf K/V, single barrier ------
// grid (B*H, SEQ/128): bh-major -> all q-blocks of one bh share an XCD's L2 KV.
// Block 256 = 4 waves; wave owns 32 q-rows (2 rowsets of 16); kv-tile 64 keys.
// K-loop: { barrier (drains tile t staging, closes buf[t+1&1] reads);
//           issue prefetch t+1 -> buf[(t+1)&1]; compute tile t on buf[t&1] }.
// V MUST stay LDS-staged (round-1: direct V reads -> FETCH 32->812MB, 4x dur).
// Round 7 (kept): l = P x ones on the MFMA pipe — 4 extra MFMA/tile replace the
// 48-inst lpart add-trees + epilogue shfl reduce (WIN: 99->91us, MfmaUtil 30->36).
// Round 8 (REVERTED): 2x-unroll + precomputed offset arrays -> compiler spilled
// the arrays to scratch (VGPR stayed 64, WRITE_SIZE 21->114MB, dur 109us).
// Const-indexed arrays spanning __syncthreads regions are NOT reliably
// register-promoted; keep addressing inline.
// LDS total = 16 (Ks dbuf) + 16 (Vts dbuf) + 8 (Ps) = 40 KB -> 4 blocks/CU.
__global__ void __launch_bounds__(256, 4) attn_kernel(const u16* __restrict__ Q,
                                                      const u16* __restrict__ Kp,
                                                      const u16* __restrict__ Vt,
                                                      u16* __restrict__ Outp) {
  __shared__ u16 Ks[2][64 * 64];     // [key][d-chunk^key&7]
  __shared__ u16 Vts[2][64 * 64];    // [d][sigma-chunk^d&7]
  __shared__ u16 Ps[4][16 * 64];     // per-wave P [row][sigma-chunk^row&7]

  int tid = threadIdx.x, wave = tid >> 6, lane = tid & 63;
  int quad = lane >> 4, l16 = lane & 15;
  int bh = blockIdx.x;
  int b = bh >> 4, h = bh & 15;
  int q0 = blockIdx.y * 128 + wave * 32;
  size_t gbase = (size_t)b * SEQ * D_MODEL;
  const u16* kbase = Kp + gbase + (size_t)h * HEAD_DIM;
  const u16* vbase = Vt + (size_t)bh * HEAD_DIM * SEQ;
  const u16* qrow = Q + gbase + (size_t)q0 * D_MODEL + (size_t)h * HEAD_DIM;

  // Q A-frags (scale pre-folded): aq[rowset][k-half]
  short8 aq[2][2];
#pragma unroll
  for (int rs = 0; rs < 2; ++rs)
#pragma unroll
    for (int dc = 0; dc < 2; ++dc)
      aq[rs][dc] = *(const short8*)(qrow + (size_t)(rs * 16 + l16) * D_MODEL + dc * 32 + quad * 8);

  // constant all-ones bf16 B-fragment (1.0 = 0x3F80) for the l = P*ones MFMA
  const short8 onesb = short8{0x3F80, 0x3F80, 0x3F80, 0x3F80,
                              0x3F80, 0x3F80, 0x3F80, 0x3F80};

  f32x4 Oacc[2][4];
  f32x4 Lacc[2];
#pragma unroll
  for (int rs = 0; rs < 2; ++rs) {
#pragma unroll
    for (int ni = 0; ni < 4; ++ni) Oacc[rs][ni] = f32x4{0.f, 0.f, 0.f, 0.f};
    Lacc[rs] = f32x4{0.f, 0.f, 0.f, 0.f};
  }

  // staging offsets (u16 units), chunk c = i*256 + tid
  size_t koff[2], voff[2];
  int dstoff[2];
#pragma unroll
  for (int i = 0; i < 2; ++i) {
    int c = i * 256 + tid;
    int krow = c >> 3, kgp = c & 7;
    koff[i] = (size_t)krow * D_MODEL + (size_t)((kgp ^ (krow & 7)) * 8);
    voff[i] = (size_t)krow * SEQ + (size_t)((kgp ^ (krow & 7)) * 8);
    dstoff[i] = i * 4096 + wave * 1024;  // bytes within one buffer
  }

  // prologue: stage tile 0 into buffer 0
#pragma unroll
  for (int i = 0; i < 2; ++i) {
    async_lds16(kbase + koff[i], (char*)Ks[0] + dstoff[i]);
    async_lds16(vbase + voff[i], (char*)Vts[0] + dstoff[i]);
  }

  constexpr int NT = SEQ / 64;  // 32 tiles
  for (int t = 0; t < NT; ++t) {
    int cur = t & 1;
    __syncthreads();  // drains tile t staging; closes prior reads of buf[cur^1]
    if (t + 1 < NT) {
      size_t kvoff = (size_t)(t + 1) * 64;
#pragma unroll
      for (int i = 0; i < 2; ++i) {
        async_lds16(kbase + kvoff * D_MODEL + koff[i], (char*)Ks[cur ^ 1] + dstoff[i]);
        async_lds16(vbase + kvoff + voff[i], (char*)Vts[cur ^ 1] + dstoff[i]);
      }
    }

    const u16* Kc = Ks[cur];
    const u16* Vc = Vts[cur];
    u16* Pw = Ps[wave];
    int x = l16 & 7;

    // K B-frags hoisted (shared across both row-sets)
    short8 kf[4][2];
#pragma unroll
    for (int sub = 0; sub < 4; ++sub) {
      const u16* kr = Kc + (sub * 16 + l16) * 64;
      kf[sub][0] = *(const short8*)(kr + ((quad ^ x) << 3));
      kf[sub][1] = *(const short8*)(kr + (((4 + quad) ^ x) << 3));
    }

    short8 pa[2][2];  // [rs][kc]
#pragma unroll
    for (int rs = 0; rs < 2; ++rs) {
      f32x4 S[4];
      __builtin_amdgcn_s_setprio(1);
#pragma unroll
      for (int sub = 0; sub < 4; ++sub) {
        f32x4 s = f32x4{0.f, 0.f, 0.f, 0.f};
        s = __builtin_amdgcn_mfma_f32_16x16x32_bf16(aq[rs][0], kf[sub][0], s, 0, 0, 0);
        s = __builtin_amdgcn_mfma_f32_16x16x32_bf16(aq[rs][1], kf[sub][1], s, 0, 0, 0);
        S[sub] = s;
      }
      __builtin_amdgcn_s_setprio(0);
#pragma unroll
      for (int r = 0; r < 4; ++r) {
        float p0 = __builtin_amdgcn_exp2f(S[0][r]);
        float p1 = __builtin_amdgcn_exp2f(S[1][r]);
        float p2 = __builtin_amdgcn_exp2f(S[2][r]);
        float p3 = __builtin_amdgcn_exp2f(S[3][r]);
        u32 lo = pack_bf16(p0, p1);
        u32 hi = pack_bf16(p2, p3);
        int row = quad * 4 + r;  // 16-row region reused by both rowsets
        int off = row * 64 + (((l16 >> 1) ^ (row & 7)) << 3) + ((l16 & 1) << 2);
        *(u32x2*)(Pw + off) = u32x2{lo, hi};
      }
      // read back this rowset's P A-frags before rs1 overwrites the region
#pragma unroll
      for (int kc = 0; kc < 2; ++kc)
        pa[rs][kc] = *(const short8*)(Pw + l16 * 64 + ((((kc << 2) + quad) ^ x) << 3));
    }

    // PV: O += P * V ; and l += P * ones on the MFMA pipe
    __builtin_amdgcn_s_setprio(1);
#pragma unroll
    for (int kc = 0; kc < 2; ++kc) {
      Lacc[0] = __builtin_amdgcn_mfma_f32_16x16x32_bf16(pa[0][kc], onesb, Lacc[0], 0, 0, 0);
      Lacc[1] = __builtin_amdgcn_mfma_f32_16x16x32_bf16(pa[1][kc], onesb, Lacc[1], 0, 0, 0);
#pragma unroll
      for (int ni = 0; ni < 4; ++ni) {
        int d = ni * 16 + l16;
        short8 bv = *(const short8*)(Vc + d * 64 + ((((kc << 2) + quad) ^ (l16 & 7)) << 3));
        Oacc[0][ni] = __builtin_amdgcn_mfma_f32_16x16x32_bf16(pa[0][kc], bv, Oacc[0][ni], 0, 0, 0);
        Oacc[1][ni] = __builtin_amdgcn_mfma_f32_16x16x32_bf16(pa[1][kc], bv, Oacc[1][ni], 0, 0, 0);
      }
    }
    __builtin_amdgcn_s_setprio(0);
  }

  // epilogue: l comes straight from Lacc (all 16 D-cols identical; row=quad*4+r)
#pragma unroll
  for (int rs = 0; rs < 2; ++rs)
#pragma unroll
    for (int r = 0; r < 4; ++r) {
      float inv = 1.0f / Lacc[rs][r];
      size_t orow = gbase + (size_t)(q0 + rs * 16 + quad * 4 + r) * D_MODEL + (size_t)h * HEAD_DIM;
#pragma unroll
      for (int ni = 0; ni < 4; ++ni)
        Outp[orow + ni * 16 + l16] = f2b(Oacc[rs][ni][r] * inv);
    }
}

// ---------------- launch ----------------
extern "C" void kernel_launch(void* const* d_in, const int* in_sizes, int n_in,
                              void* d_out, int out_size, void* d_ws, size_t ws_size,
                              hipStream_t stream) {
  const float* x  = (const float*)d_in[0];
  const float* y  = (const float*)d_in[1];
  const float* wq = (const float*)d_in[2];
  const float* bq = (const float*)d_in[3];
  const float* wk = (const float*)d_in[4];
  const float* bk = (const float*)d_in[5];
  const float* wv = (const float*)d_in[6];
  const float* bv = (const float*)d_in[7];
  const float* wo = (const float*)d_in[8];
  const float* bo = (const float*)d_in[9];
  float* out = (float*)d_out;

  char* ws = (char*)d_ws;
  const size_t SZ_ACT = (size_t)ROWS * D_MODEL * 2;     // 16 MiB
  const size_t SZ_W   = (size_t)D_MODEL * D_MODEL * 2;  // 2 MiB
  u16* xb  = (u16*)(ws);
  u16* yb  = (u16*)(ws + SZ_ACT);
  u16* wT  = (u16*)(ws + 2 * SZ_ACT);
  u16* wqT = wT;
  u16* wkT = (u16*)(ws + 2 * SZ_ACT + SZ_W);
  u16* wvT = (u16*)(ws + 2 * SZ_ACT + 2 * SZ_W);
  u16* woT = (u16*)(ws + 2 * SZ_ACT + 3 * SZ_W);
  u16* qb  = (u16*)(ws + 2 * SZ_ACT + 4 * SZ_W);
  u16* kb  = (u16*)(ws + 3 * SZ_ACT + 4 * SZ_W);
  u16* vt  = (u16*)(ws + 4 * SZ_ACT + 4 * SZ_W);
  u16* ao  = (u16*)(ws + 5 * SZ_ACT + 4 * SZ_W);

  cvt_kernel<<<dim3(8192, 2), 256, 0, stream>>>(x, y, xb, yb);
  wtrans_kernel<<<dim3(16, 16, 4), 256, 0, stream>>>(wq, wk, wv, wo, wT);
  gemm_qkv_kernel<<<dim3(512, 3), 256, 0, stream>>>(xb, yb, wqT, wkT, wvT, bq, bk, bv, qb, kb, vt);
  attn_kernel<<<dim3(64, 16), 256, 0, stream>>>(qb, kb, vt, ao);
  gemm_o_kernel<<<dim3(8, 64), 256, 0, stream>>>(ao, woT, bo, out);
}

// Round 10
// 298.145 us; speedup vs baseline: 1.0862x; 1.0581x over previous
//
#include <hip/hip_runtime.h>
#include <stdint.h>

#define D_MODEL 1024
#define NHEAD 16
#define HEAD_DIM 64
#define BATCH 4
#define SEQ 2048
#define ROWS (BATCH*SEQ)   // 8192

typedef __attribute__((ext_vector_type(8))) short short8;
typedef __attribute__((ext_vector_type(4))) float f32x4;
typedef __attribute__((ext_vector_type(2))) unsigned int u32x2;
typedef unsigned short u16;
typedef unsigned int u32;

// log2(e)/8 folded into Q at projection time
#define QSCALE 0.18033688011112042f

// fp32 -> bf16 round-to-nearest-even
__device__ __forceinline__ u16 f2b(float f) {
  union { float f; uint32_t u; } in; in.f = f;
  uint32_t u = in.u;
  return (u16)((u + 0x7FFFu + ((u >> 16) & 1u)) >> 16);
}

// async global->LDS, 16B/lane; HW dest = wave-uniform base + lane*16
__device__ __forceinline__ void async_lds16(const void* g, void* l) {
  __builtin_amdgcn_global_load_lds(
      (const __attribute__((address_space(1))) uint32_t*)g,
      (__attribute__((address_space(3))) uint32_t*)l,
      16, 0, 0);
}

// pack two f32 into bf16x2 (round-half-up)
__device__ __forceinline__ u32 pack_bf16(float lo, float hi) {
  union { float f; uint32_t u; } a, b; a.f = lo; b.f = hi;
  return __builtin_amdgcn_perm(b.u + 0x8000u, a.u + 0x8000u, 0x07060302u);
}

// ---------------- fused pre-pass: bf16 convert (x,y) + weight transpose ----------
// ROUND 10: cvt_kernel + wtrans_kernel fused into ONE launch (5 -> 4 kernels).
// Sum-of-dispatches (~235us) vs wall (~315us) shows ~15-20us per kernel boundary;
// cvt and wtrans are independent so they share a launch and fill CUs together.
// Flat grid: blocks [0,16384) = cvt (2 planes x 8192), [16384,17408) = wtrans.
__global__ void __launch_bounds__(256) pre_kernel(const float* __restrict__ x,
                                                  const float* __restrict__ y,
                                                  const float* __restrict__ wq,
                                                  const float* __restrict__ wk,
                                                  const float* __restrict__ wv,
                                                  const float* __restrict__ wo,
                                                  u16* __restrict__ xb,
                                                  u16* __restrict__ yb,
                                                  u16* __restrict__ wtbase) {
  __shared__ u16 tile[64 * 65];
  int gid = blockIdx.x;
  if (gid < 16384) {
    // cvt: plane 0 = x, plane 1 = y
    const float* in = (gid >= 8192) ? y : x;
    u16* out = (gid >= 8192) ? yb : xb;
    int i = (gid & 8191) * 256 + threadIdx.x;
    float4 v = ((const float4*)in)[i];
    ushort4 o;
    o.x = f2b(v.x); o.y = f2b(v.y); o.z = f2b(v.z); o.w = f2b(v.w);
    ((ushort4*)out)[i] = o;
  } else {
    // wtrans: idx in [0,1024): z = weight, rem = 16x16 tile grid
    int idx = gid - 16384;
    int z = idx >> 8;
    int rem = idx & 255;
    const float* w = (z == 0) ? wq : (z == 1 ? wk : (z == 2 ? wv : wo));
    u16* wt = wtbase + (size_t)z * D_MODEL * D_MODEL;
    int t = threadIdx.x;
    int c = t & 63, rb = t >> 6;
    int k0 = (rem & 15) * 64, n0 = (rem >> 4) * 64;
#pragma unroll
    for (int i = 0; i < 16; ++i) {
      int r = rb + i * 4;
      tile[c * 65 + r] = f2b(w[(size_t)(k0 + r) * D_MODEL + n0 + c]);
    }
    __syncthreads();
#pragma unroll
    for (int i = 0; i < 16; ++i) {
      int r = rb + i * 4;
      wt[(size_t)(n0 + r) * D_MODEL + k0 + c] = tile[r * 65 + c];
    }
  }
}

// ---------------- GEMM core: C[M][N] = A[M][K] * Bt[N][K]^T + bias ----------------
// Serial BK=64 loop (m97 structure, round-5 verified best) + caller-hoisted
// 32 KB LDS (round 4: per-instantiation __shared__ dup'd to 64 KB -> 2 blk/CU).
// 128x128 tile, 4 waves (2x2), 4x4 accs.
// MODE 0 (bf16 out) / MODE 1 (f32 out): OPERAND-SWAPPED (weights in MFMA-A slot)
//   so D's reg-dim = output columns -> vectorized 8B/16B stores.
// MODE 2: V^T sigma-layout out, natural orientation, packed across ni.
template <int MODE>
__device__ __forceinline__ void gemm_bt_core(const u16* __restrict__ A,
                                             const u16* __restrict__ Bt,
                                             const float* __restrict__ bias,
                                             void* __restrict__ Cout, float scale,
                                             int m0, int n0,
                                             u16 (* __restrict__ As)[128 * 32],
                                             u16 (* __restrict__ Bs)[128 * 32]) {
  constexpr int K = 1024, N = 1024;
  constexpr bool SWAP = (MODE != 2);
  int tid = threadIdx.x;
  int wave = tid >> 6, lane = tid & 63;
  int quad = lane >> 4, l16 = lane & 15;
  int wm = wave & 1, wn = wave >> 1;

  f32x4 acc[4][4];
#pragma unroll
  for (int p = 0; p < 4; ++p)
#pragma unroll
    for (int q = 0; q < 4; ++q) acc[p][q] = f32x4{0.f, 0.f, 0.f, 0.f};

  int srow = lane >> 2;
  int scol = (lane & 3) * 16;  // bytes

  for (int k0 = 0; k0 < K; k0 += 64) {
#pragma unroll
    for (int kh = 0; kh < 2; ++kh) {
#pragma unroll
      for (int i = 0; i < 2; ++i) {
        int c = wave * 2 + i;
        const char* ga = (const char*)(A + (size_t)(m0 + c * 16 + srow) * K + k0 + kh * 32) + scol;
        async_lds16(ga, (char*)As[kh] + c * 1024);
        const char* gb = (const char*)(Bt + (size_t)(n0 + c * 16 + srow) * K + k0 + kh * 32) + scol;
        async_lds16(gb, (char*)Bs[kh] + c * 1024);
      }
    }
    __syncthreads();  // drains staging

#pragma unroll
    for (int kh = 0; kh < 2; ++kh) {
      short8 fa[4], fb[4];
#pragma unroll
      for (int p = 0; p < 4; ++p)
        fa[p] = SWAP
          ? *(const short8*)(Bs[kh] + (wn * 64 + p * 16 + l16) * 32 + quad * 8)
          : *(const short8*)(As[kh] + (wm * 64 + p * 16 + l16) * 32 + quad * 8);
#pragma unroll
      for (int q = 0; q < 4; ++q)
        fb[q] = SWAP
          ? *(const short8*)(As[kh] + (wm * 64 + q * 16 + l16) * 32 + quad * 8)
          : *(const short8*)(Bs[kh] + (wn * 64 + q * 16 + l16) * 32 + quad * 8);
#pragma unroll
      for (int p = 0; p < 4; ++p)
#pragma unroll
        for (int q = 0; q < 4; ++q)
          acc[p][q] = __builtin_amdgcn_mfma_f32_16x16x32_bf16(fa[p], fb[q], acc[p][q], 0, 0, 0);
    }
    __syncthreads();
  }

  if (MODE == 2) {
    // acc[p][q]: D-row (quad*4+r) = d-dim (wvT row), D-col (l16) = s within q*16 block.
    int sblk = n0 + wn * 64;               // 64-aligned s block; all s in same batch b
    int bb = sblk >> 11;
    int ssb = sblk & 2047;
#pragma unroll
    for (int p = 0; p < 4; ++p) {
      int dbase = m0 + wm * 64 + p * 16 + quad * 4;
      float4 b4 = *(const float4*)(bias + dbase);
#pragma unroll
      for (int r = 0; r < 4; ++r) {
        int d = dbase + r;
        float bv = ((const float*)&b4)[r];
        u32 lo = pack_bf16(acc[p][0][r] + bv, acc[p][1][r] + bv);
        u32 hi = pack_bf16(acc[p][2][r] + bv, acc[p][3][r] + bv);
        size_t vtrow = ((size_t)bb * 16 + (d >> 6)) * 64 + (d & 63);
        *(u32x2*)((u16*)Cout + vtrow * 2048 + ssb + 4 * l16) = u32x2{lo, hi};
      }
    }
  } else {
    // SWAPPED: acc[p][q]: D-row (quad*4+r) = out-col n, D-col (l16) = out-row m.
#pragma unroll
    for (int p = 0; p < 4; ++p) {
      int nbase = n0 + wn * 64 + p * 16 + quad * 4;
      float4 b4 = *(const float4*)(bias + nbase);
#pragma unroll
      for (int q = 0; q < 4; ++q) {
        size_t mrow = (size_t)(m0 + wm * 64 + q * 16 + l16);
        float v0 = (acc[p][q][0] + b4.x) * scale;
        float v1 = (acc[p][q][1] + b4.y) * scale;
        float v2 = (acc[p][q][2] + b4.z) * scale;
        float v3 = (acc[p][q][3] + b4.w) * scale;
        if (MODE == 1) {
          *(f32x4*)((float*)Cout + mrow * N + nbase) = f32x4{v0, v1, v2, v3};
        } else {
          *(u32x2*)((u16*)Cout + mrow * N + nbase) = u32x2{pack_bf16(v0, v1), pack_bf16(v2, v3)};
        }
      }
    }
  }
}

// QKV fused: grid (512, 3). z=0: Q=x*wq (scaled); z=1: K=y*wk; z=2: V^T sigma
// T1 XCD swizzle (round 6, WIN): linear id = bx + z*512 -> XCD = bx & 7.
// Each XCD owns a contiguous 8-m-block stripe (2 MB of the 16 MB activation) x
// all 8 weight n-blocks -> per-XCD working set ~4 MB = one L2. z=2 swaps roles.
__global__ void __launch_bounds__(256, 4) gemm_qkv_kernel(
    const u16* __restrict__ xb, const u16* __restrict__ yb,
    const u16* __restrict__ wqT, const u16* __restrict__ wkT, const u16* __restrict__ wvT,
    const float* __restrict__ bq, const float* __restrict__ bk, const float* __restrict__ bv,
    u16* __restrict__ q, u16* __restrict__ k, u16* __restrict__ vt) {
  // single 32 KB allocation shared by all gemm_bt_core instantiations
  __shared__ u16 As[2][128 * 32];
  __shared__ u16 Bs[2][128 * 32];
  int bx = blockIdx.x, z = blockIdx.y;
  int xcd = bx & 7, i = bx >> 3;
  int stripe = (xcd * 8 + (i >> 3)) * 128;  // 64 blocks of the 16MB-array dim
  int other  = (i & 7) * 128;               // 8 blocks of the 1K weight dim
  if (z == 0) {
    gemm_bt_core<0>(xb, wqT, bq, q, QSCALE, stripe, other, As, Bs);
  } else if (z == 1) {
    gemm_bt_core<0>(yb, wkT, bk, k, 1.0f, stripe, other, As, Bs);
  } else {
    gemm_bt_core<2>(wvT, yb, bv, vt, 1.0f, other, stripe, As, Bs);
  }
}

// grid (8, 64): XCD bx owns m-stripe bx*8+(by>>3), n = by&7 (bijective).
__global__ void __launch_bounds__(256, 4) gemm_o_kernel(const u16* __restrict__ ao,
                                                        const u16* __restrict__ woT,
                                                        const float* __restrict__ bo,
                                                        float* __restrict__ out) {
  __shared__ u16 As[2][128 * 32];
  __shared__ u16 Bs[2][128 * 32];
  int bx = blockIdx.x, by = blockIdx.y;
  int m0 = (bx * 8 + (by >> 3)) * 128;
  int n0 = (by & 7) * 128;
  gemm_bt_core<1>(ao, woT, bo, out, 1.0f, m0, n0, As, Bs);
}

// ---------------- flash attention: no-max softmax, dbuf K/V, single barrier ------
// grid (B*H, SEQ/128): bh-major -> all q-blocks of one bh share an XCD's L2 KV.
// Block 256 = 4 waves; wave owns 32 q-rows (2 rowsets of 16); kv-tile 64 keys.
// K-loop: { barrier (drains tile t staging, closes buf[t+1&1] reads);
//           issue prefetch t+1 -> buf[(t+1)&1]; compute tile t on buf[t&1] }.
// V MUST stay LDS-staged (round-1: direct V reads -> FETCH 32->812MB, 4x dur).
// Round 7 (kept): l = P x ones on the MFMA pipe (WIN: 99->91us, MfmaUtil 30->36).
// Round 8 (REVERTED): offset-array hoist spilled to scratch (WRITE 21->114MB).
// ROUND 10: prefetch addresses as 4 NAMED incrementing pointers (no arrays, no
// unroll) -- removes the per-tile (t+1)*64*D_MODEL 64-bit mul-add chains without
// round-8's spill trigger. Occupancy note: grid = 1024 blocks = exactly 4/CU
// resident; LDS 40KB also caps 4/CU -> occupancy is at its structural limit.
// LDS total = 16 (Ks dbuf) + 16 (Vts dbuf) + 8 (Ps) = 40 KB.
__global__ void __launch_bounds__(256, 4) attn_kernel(const u16* __restrict__ Q,
                                                      const u16* __restrict__ Kp,
                                                      const u16* __restrict__ Vt,
                                                      u16* __restrict__ Outp) {
  __shared__ u16 Ks[2][64 * 64];     // [key][d-chunk^key&7]
  __shared__ u16 Vts[2][64 * 64];    // [d][sigma-chunk^d&7]
  __shared__ u16 Ps[4][16 * 64];     // per-wave P [row][sigma-chunk^row&7]

  int tid = threadIdx.x, wave = tid >> 6, lane = tid & 63;
  int quad = lane >> 4, l16 = lane & 15;
  int bh = blockIdx.x;
  int b = bh >> 4, h = bh & 15;
  int q0 = blockIdx.y * 128 + wave * 32;
  size_t gbase = (size_t)b * SEQ * D_MODEL;
  const u16* kbase = Kp + gbase + (size_t)h * HEAD_DIM;
  const u16* vbase = Vt + (size_t)bh * HEAD_DIM * SEQ;
  const u16* qrow = Q + gbase + (size_t)q0 * D_MODEL + (size_t)h * HEAD_DIM;

  // Q A-frags (scale pre-folded): aq[rowset][k-half]
  short8 aq[2][2];
#pragma unroll
  for (int rs = 0; rs < 2; ++rs)
#pragma unroll
    for (int dc = 0; dc < 2; ++dc)
      aq[rs][dc] = *(const short8*)(qrow + (size_t)(rs * 16 + l16) * D_MODEL + dc * 32 + quad * 8);

  // constant all-ones bf16 B-fragment (1.0 = 0x3F80) for the l = P*ones MFMA
  const short8 onesb = short8{0x3F80, 0x3F80, 0x3F80, 0x3F80,
                              0x3F80, 0x3F80, 0x3F80, 0x3F80};

  f32x4 Oacc[2][4];
  f32x4 Lacc[2];
#pragma unroll
  for (int rs = 0; rs < 2; ++rs) {
#pragma unroll
    for (int ni = 0; ni < 4; ++ni) Oacc[rs][ni] = f32x4{0.f, 0.f, 0.f, 0.f};
    Lacc[rs] = f32x4{0.f, 0.f, 0.f, 0.f};
  }

  // staging offsets (u16 units) as named scalars; chunk c = i*256 + tid
  int c0 = tid, c1 = 256 + tid;
  int krow0 = c0 >> 3, kgp0 = c0 & 7;
  int krow1 = c1 >> 3, kgp1 = c1 & 7;
  size_t koff0 = (size_t)krow0 * D_MODEL + (size_t)((kgp0 ^ (krow0 & 7)) * 8);
  size_t koff1 = (size_t)krow1 * D_MODEL + (size_t)((kgp1 ^ (krow1 & 7)) * 8);
  size_t voff0 = (size_t)krow0 * SEQ + (size_t)((kgp0 ^ (krow0 & 7)) * 8);
  size_t voff1 = (size_t)krow1 * SEQ + (size_t)((kgp1 ^ (krow1 & 7)) * 8);
  int dst0 = wave * 1024;          // bytes within one buffer
  int dst1 = 4096 + wave * 1024;

  // prologue: stage tile 0 into buffer 0; prefetch pointers start at tile 1
  async_lds16(kbase + koff0, (char*)Ks[0] + dst0);
  async_lds16(kbase + koff1, (char*)Ks[0] + dst1);
  async_lds16(vbase + voff0, (char*)Vts[0] + dst0);
  async_lds16(vbase + voff1, (char*)Vts[0] + dst1);
  const u16* kp0 = kbase + (size_t)64 * D_MODEL + koff0;
  const u16* kp1 = kbase + (size_t)64 * D_MODEL + koff1;
  const u16* vp0 = vbase + 64 + voff0;
  const u16* vp1 = vbase + 64 + voff1;

  constexpr int NT = SEQ / 64;  // 32 tiles
  for (int t = 0; t < NT; ++t) {
    int cur = t & 1;
    __syncthreads();  // drains tile t staging; closes prior reads of buf[cur^1]
    if (t + 1 < NT) {
      async_lds16(kp0, (char*)Ks[cur ^ 1] + dst0);
      async_lds16(kp1, (char*)Ks[cur ^ 1] + dst1);
      async_lds16(vp0, (char*)Vts[cur ^ 1] + dst0);
      async_lds16(vp1, (char*)Vts[cur ^ 1] + dst1);
      kp0 += (size_t)64 * D_MODEL;
      kp1 += (size_t)64 * D_MODEL;
      vp0 += 64;
      vp1 += 64;
    }

    const u16* Kc = Ks[cur];
    const u16* Vc = Vts[cur];
    u16* Pw = Ps[wave];
    int x = l16 & 7;

    // K B-frags hoisted (shared across both row-sets)
    short8 kf[4][2];
#pragma unroll
    for (int sub = 0; sub < 4; ++sub) {
      const u16* kr = Kc + (sub * 16 + l16) * 64;
      kf[sub][0] = *(const short8*)(kr + ((quad ^ x) << 3));
      kf[sub][1] = *(const short8*)(kr + (((4 + quad) ^ x) << 3));
    }

    short8 pa[2][2];  // [rs][kc]
#pragma unroll
    for (int rs = 0; rs < 2; ++rs) {
      f32x4 S[4];
      __builtin_amdgcn_s_setprio(1);
#pragma unroll
      for (int sub = 0; sub < 4; ++sub) {
        f32x4 s = f32x4{0.f, 0.f, 0.f, 0.f};
        s = __builtin_amdgcn_mfma_f32_16x16x32_bf16(aq[rs][0], kf[sub][0], s, 0, 0, 0);
        s = __builtin_amdgcn_mfma_f32_16x16x32_bf16(aq[rs][1], kf[sub][1], s, 0, 0, 0);
        S[sub] = s;
      }
      __builtin_amdgcn_s_setprio(0);
#pragma unroll
      for (int r = 0; r < 4; ++r) {
        float p0 = __builtin_amdgcn_exp2f(S[0][r]);
        float p1 = __builtin_amdgcn_exp2f(S[1][r]);
        float p2 = __builtin_amdgcn_exp2f(S[2][r]);
        float p3 = __builtin_amdgcn_exp2f(S[3][r]);
        u32 lo = pack_bf16(p0, p1);
        u32 hi = pack_bf16(p2, p3);
        int row = quad * 4 + r;  // 16-row region reused by both rowsets
        int off = row * 64 + (((l16 >> 1) ^ (row & 7)) << 3) + ((l16 & 1) << 2);
        *(u32x2*)(Pw + off) = u32x2{lo, hi};
      }
      // read back this rowset's P A-frags before rs1 overwrites the region
#pragma unroll
      for (int kc = 0; kc < 2; ++kc)
        pa[rs][kc] = *(const short8*)(Pw + l16 * 64 + ((((kc << 2) + quad) ^ x) << 3));
    }

    // PV: O += P * V ; and l += P * ones on the MFMA pipe
    __builtin_amdgcn_s_setprio(1);
#pragma unroll
    for (int kc = 0; kc < 2; ++kc) {
      Lacc[0] = __builtin_amdgcn_mfma_f32_16x16x32_bf16(pa[0][kc], onesb, Lacc[0], 0, 0, 0);
      Lacc[1] = __builtin_amdgcn_mfma_f32_16x16x32_bf16(pa[1][kc], onesb, Lacc[1], 0, 0, 0);
#pragma unroll
      for (int ni = 0; ni < 4; ++ni) {
        int d = ni * 16 + l16;
        short8 bv = *(const short8*)(Vc + d * 64 + ((((kc << 2) + quad) ^ (l16 & 7)) << 3));
        Oacc[0][ni] = __builtin_amdgcn_mfma_f32_16x16x32_bf16(pa[0][kc], bv, Oacc[0][ni], 0, 0, 0);
        Oacc[1][ni] = __builtin_amdgcn_mfma_f32_16x16x32_bf16(pa[1][kc], bv, Oacc[1][ni], 0, 0, 0);
      }
    }
    __builtin_amdgcn_s_setprio(0);
  }

  // epilogue: l comes straight from Lacc (all 16 D-cols identical; row=quad*4+r)
#pragma unroll
  for (int rs = 0; rs < 2; ++rs)
#pragma unroll
    for (int r = 0; r < 4; ++r) {
      float inv = 1.0f / Lacc[rs][r];
      size_t orow = gbase + (size_t)(q0 + rs * 16 + quad * 4 + r) * D_MODEL + (size_t)h * HEAD_DIM;
#pragma unroll
      for (int ni = 0; ni < 4; ++ni)
        Outp[orow + ni * 16 + l16] = f2b(Oacc[rs][ni][r] * inv);
    }
}

// ---------------- launch ----------------
extern "C" void kernel_launch(void* const* d_in, const int* in_sizes, int n_in,
                              void* d_out, int out_size, void* d_ws, size_t ws_size,
                              hipStream_t stream) {
  const float* x  = (const float*)d_in[0];
  const float* y  = (const float*)d_in[1];
  const float* wq = (const float*)d_in[2];
  const float* bq = (const float*)d_in[3];
  const float* wk = (const float*)d_in[4];
  const float* bk = (const float*)d_in[5];
  const float* wv = (const float*)d_in[6];
  const float* bv = (const float*)d_in[7];
  const float* wo = (const float*)d_in[8];
  const float* bo = (const float*)d_in[9];
  float* out = (float*)d_out;

  char* ws = (char*)d_ws;
  const size_t SZ_ACT = (size_t)ROWS * D_MODEL * 2;     // 16 MiB
  const size_t SZ_W   = (size_t)D_MODEL * D_MODEL * 2;  // 2 MiB
  u16* xb  = (u16*)(ws);
  u16* yb  = (u16*)(ws + SZ_ACT);
  u16* wT  = (u16*)(ws + 2 * SZ_ACT);
  u16* wqT = wT;
  u16* wkT = (u16*)(ws + 2 * SZ_ACT + SZ_W);
  u16* wvT = (u16*)(ws + 2 * SZ_ACT + 2 * SZ_W);
  u16* woT = (u16*)(ws + 2 * SZ_ACT + 3 * SZ_W);
  u16* qb  = (u16*)(ws + 2 * SZ_ACT + 4 * SZ_W);
  u16* kb  = (u16*)(ws + 3 * SZ_ACT + 4 * SZ_W);
  u16* vt  = (u16*)(ws + 4 * SZ_ACT + 4 * SZ_W);
  u16* ao  = (u16*)(ws + 5 * SZ_ACT + 4 * SZ_W);

  pre_kernel<<<dim3(17408), 256, 0, stream>>>(x, y, wq, wk, wv, wo, xb, yb, wT);
  gemm_qkv_kernel<<<dim3(512, 3), 256, 0, stream>>>(xb, yb, wqT, wkT, wvT, bq, bk, bv, qb, kb, vt);
  attn_kernel<<<dim3(64, 16), 256, 0, stream>>>(qb, kb, vt, ao);
  gemm_o_kernel<<<dim3(8, 64), 256, 0, stream>>>(ao, woT, bo, out);
}